// Round 1
// baseline (1960.560 us; speedup 1.0000x reference)
//
#include <hip/hip_runtime.h>

#define NPTS 8192
#define NSAMP 1024
#define NBATCH 8
#define KNB 32

// Exact-match squared distance: ((dx*dx + dy*dy) + dz*dz) with no FMA contraction,
// matching XLA's f32 reduce over the last axis (left-assoc, separate mul/add).
__device__ __forceinline__ float sqdist_rn(float px, float py, float pz,
                                           float qx, float qy, float qz) {
  float dx = px - qx, dy = py - qy, dz = pz - qz;
  return __fadd_rn(__fadd_rn(__fmul_rn(dx, dx), __fmul_rn(dy, dy)), __fmul_rn(dz, dz));
}

// ---------------------------------------------------------------------------
// Kernel 1: farthest point sampling. One block per batch, 512 threads,
// 16 points per thread held in registers. Emits new_xyz (B,3,S) directly
// (exact copies of input coords, so downstream bitwise-matches the reference).
// Scan semantics: idxs[0]=0; at step t emit `last`, then
// d=min(d, dist2(pts, pts[last])), last=argmax(d) (first-max tie-break).
// ---------------------------------------------------------------------------
__global__ __launch_bounds__(512) void fps_kernel(const float* __restrict__ xyz,
                                                  float* __restrict__ out_newxyz) {
  __shared__ float red_v[8];
  __shared__ int red_i[8];
  __shared__ float ls[3];  // coords of current selected point

  const int b = blockIdx.x;
  const int tid = threadIdx.x;
  const float* xb = xyz + (size_t)b * 3 * NPTS;

  float X[16], Y[16], Z[16], Dm[16];
#pragma unroll
  for (int j = 0; j < 16; j++) {
    int n = tid + j * 512;
    X[j] = xb[n];
    Y[j] = xb[NPTS + n];
    Z[j] = xb[2 * NPTS + n];
    Dm[j] = 1e10f;
  }
  if (tid == 0) { ls[0] = X[0]; ls[1] = Y[0]; ls[2] = Z[0]; }  // point 0
  __syncthreads();

  for (int t = 0; t < NSAMP; t++) {
    float sx = ls[0], sy = ls[1], sz = ls[2];
    if (tid == 0) {
      out_newxyz[(b * 3 + 0) * NSAMP + t] = sx;
      out_newxyz[(b * 3 + 1) * NSAMP + t] = sy;
      out_newxyz[(b * 3 + 2) * NSAMP + t] = sz;
    }
    // distance update + per-thread argmax (ascending n => first-max tie-break)
    float bv = -1.0f;
    int bi = NPTS;
#pragma unroll
    for (int j = 0; j < 16; j++) {
      float dd = sqdist_rn(X[j], Y[j], Z[j], sx, sy, sz);
      float dm = fminf(Dm[j], dd);
      Dm[j] = dm;
      if (dm > bv) { bv = dm; bi = tid + j * 512; }
    }
    // wave reduction (64 lanes), tie-break to lowest index
#pragma unroll
    for (int m = 1; m < 64; m <<= 1) {
      float ov = __shfl_xor(bv, m, 64);
      int oi = __shfl_xor(bi, m, 64);
      if (ov > bv || (ov == bv && oi < bi)) { bv = ov; bi = oi; }
    }
    int wv = tid >> 6;
    if ((tid & 63) == 0) { red_v[wv] = bv; red_i[wv] = bi; }
    __syncthreads();
    // every wave redundantly reduces the 8 wave-winners so all threads learn fi
    int lane = tid & 63;
    float fv = red_v[lane & 7];
    int fi = red_i[lane & 7];
#pragma unroll
    for (int m = 1; m < 8; m <<= 1) {
      float ov = __shfl_xor(fv, m, 64);
      int oi = __shfl_xor(fi, m, 64);
      if (ov > fv || (ov == fv && oi < fi)) { fv = ov; fi = oi; }
    }
    // winner thread publishes the selected point's coords (static-index select,
    // avoids scratch from runtime register indexing)
    if (tid == (fi & 511)) {
      int jj = fi >> 9;
      float vx = 0.f, vy = 0.f, vz = 0.f;
#pragma unroll
      for (int j = 0; j < 16; j++)
        if (j == jj) { vx = X[j]; vy = Y[j]; vz = Z[j]; }
      ls[0] = vx; ls[1] = vy; ls[2] = vz;
    }
    __syncthreads();
  }
}

// ---------------------------------------------------------------------------
// Kernel 2: ball query + attention mean. One wave per (b,s). Scans points in
// ascending index order in chunks of 64, collects the first K in-radius
// indices (ballot + prefix popcount), pads with the first hit.
// ---------------------------------------------------------------------------
__global__ __launch_bounds__(256) void ballq_kernel(const float* __restrict__ xyz,
                                                    const float* __restrict__ att,
                                                    const float* __restrict__ newxyz,
                                                    int* __restrict__ idx_out,
                                                    float* __restrict__ att_out) {
  __shared__ int rowbuf[4][KNB];
  const int wv = threadIdx.x >> 6;
  const int lane = threadIdx.x & 63;
  const int g = blockIdx.x * 4 + wv;  // b*NSAMP + s
  const int b = g >> 10;
  const int s = g & 1023;
  const float* xb = xyz + (size_t)b * 3 * NPTS;

  float qx = newxyz[(b * 3 + 0) * NSAMP + s];
  float qy = newxyz[(b * 3 + 1) * NSAMP + s];
  float qz = newxyz[(b * 3 + 2) * NSAMP + s];

  int have = 0;
  int firstn = 0;
  for (int c = 0; c < NPTS / 64; c++) {
    int n = c * 64 + lane;
    float dd = sqdist_rn(xb[n], xb[NPTS + n], xb[2 * NPTS + n], qx, qy, qz);
    bool inb = (dd <= 0.04f);
    unsigned long long m = __ballot(inb);
    if (have == 0 && m != 0ull) firstn = c * 64 + __builtin_ctzll(m);
    int pre = __popcll(m & ((1ull << lane) - 1ull));
    if (inb && (have + pre) < KNB) rowbuf[wv][have + pre] = n;
    have += __popcll(m);
    if (have >= KNB) break;
  }
  if (have > KNB) have = KNB;
  if (lane < KNB && lane >= have) rowbuf[wv][lane] = firstn;  // pad

  float av = 0.0f;
  if (lane < KNB) {
    int myidx = rowbuf[wv][lane];
    idx_out[(size_t)g * KNB + lane] = myidx;
    av = att[(size_t)b * NPTS + myidx];
  }
#pragma unroll
  for (int m = 1; m < 64; m <<= 1) av += __shfl_xor(av, m, 64);
  if (lane == 0) att_out[g] = av * 0.03125f;  // mean over K=32 (exact /32)
}

// ---------------------------------------------------------------------------
// Kernel 3: gather features + 3-layer MLP + max over K. One 256-thread block
// per (b,s). feat [67][32] and h [64][36] (padded stride) in LDS; weights
// streamed from global (L1/L2 broadcast). f32 fmaf throughout.
// ---------------------------------------------------------------------------
__global__ __launch_bounds__(256) void mlp_kernel(
    const float* __restrict__ xyz, const float* __restrict__ pts,
    const float* __restrict__ newxyz, const int* __restrict__ idx,
    const float* __restrict__ w0, const float* __restrict__ b0,
    const float* __restrict__ w1, const float* __restrict__ b1,
    const float* __restrict__ w2, const float* __restrict__ b2,
    float* __restrict__ out_np) {
  const int g = blockIdx.x;
  const int b = g >> 10;
  const int s = g & 1023;
  const int t = threadIdx.x;

  __shared__ __align__(16) float feat[67 * 32];
  __shared__ __align__(16) float h0s[64 * 36];
  __shared__ __align__(16) float h1s[64 * 36];
  __shared__ int sidx[KNB];

  if (t < KNB) sidx[t] = idx[(size_t)g * KNB + t];
  __syncthreads();

  // gather: rows 0..2 = g_norm (xyz - query), rows 3..66 = point features
  {
    int k = t & 31, rg = t >> 5;
    int n = sidx[k];
    const float* pb = pts + (size_t)b * 64 * NPTS;
    for (int r = rg; r < 67; r += 8) {
      float v;
      if (r < 3)
        v = xyz[((size_t)b * 3 + r) * NPTS + n] - newxyz[(b * 3 + r) * NSAMP + s];
      else
        v = pb[(size_t)(r - 3) * NPTS + n];
      feat[r * 32 + k] = v;
    }
  }
  __syncthreads();

  const int kq = t & 7;   // k block = 4*kq .. +4
  const int og = t >> 3;  // o = 2*og, 2*og+1

  // ---- layer 0: 67 -> 64 ----
  {
    float a0[8];
    float bu = b0[2 * og], bw = b0[2 * og + 1];
    a0[0] = a0[1] = a0[2] = a0[3] = bu;
    a0[4] = a0[5] = a0[6] = a0[7] = bw;
    const float* wr0 = w0 + (2 * og) * 67;
    const float* wr1 = wr0 + 67;
    for (int c = 0; c < 67; c++) {
      float4 f = *(const float4*)&feat[c * 32 + kq * 4];
      float u = wr0[c], v = wr1[c];
      a0[0] = fmaf(u, f.x, a0[0]); a0[1] = fmaf(u, f.y, a0[1]);
      a0[2] = fmaf(u, f.z, a0[2]); a0[3] = fmaf(u, f.w, a0[3]);
      a0[4] = fmaf(v, f.x, a0[4]); a0[5] = fmaf(v, f.y, a0[5]);
      a0[6] = fmaf(v, f.z, a0[6]); a0[7] = fmaf(v, f.w, a0[7]);
    }
    float4 r0, r1;
    r0.x = fmaxf(a0[0], 0.f); r0.y = fmaxf(a0[1], 0.f);
    r0.z = fmaxf(a0[2], 0.f); r0.w = fmaxf(a0[3], 0.f);
    r1.x = fmaxf(a0[4], 0.f); r1.y = fmaxf(a0[5], 0.f);
    r1.z = fmaxf(a0[6], 0.f); r1.w = fmaxf(a0[7], 0.f);
    *(float4*)&h0s[(2 * og) * 36 + kq * 4] = r0;
    *(float4*)&h0s[(2 * og + 1) * 36 + kq * 4] = r1;
  }
  __syncthreads();

  // ---- layer 1: 64 -> 64 ----
  {
    float a1[8];
    float bu = b1[2 * og], bw = b1[2 * og + 1];
    a1[0] = a1[1] = a1[2] = a1[3] = bu;
    a1[4] = a1[5] = a1[6] = a1[7] = bw;
    const float* wr0 = w1 + (2 * og) * 64;
    const float* wr1 = wr0 + 64;
    for (int c = 0; c < 64; c++) {
      float4 f = *(const float4*)&h0s[c * 36 + kq * 4];
      float u = wr0[c], v = wr1[c];
      a1[0] = fmaf(u, f.x, a1[0]); a1[1] = fmaf(u, f.y, a1[1]);
      a1[2] = fmaf(u, f.z, a1[2]); a1[3] = fmaf(u, f.w, a1[3]);
      a1[4] = fmaf(v, f.x, a1[4]); a1[5] = fmaf(v, f.y, a1[5]);
      a1[6] = fmaf(v, f.z, a1[6]); a1[7] = fmaf(v, f.w, a1[7]);
    }
    float4 r0, r1;
    r0.x = fmaxf(a1[0], 0.f); r0.y = fmaxf(a1[1], 0.f);
    r0.z = fmaxf(a1[2], 0.f); r0.w = fmaxf(a1[3], 0.f);
    r1.x = fmaxf(a1[4], 0.f); r1.y = fmaxf(a1[5], 0.f);
    r1.z = fmaxf(a1[6], 0.f); r1.w = fmaxf(a1[7], 0.f);
    *(float4*)&h1s[(2 * og) * 36 + kq * 4] = r0;
    *(float4*)&h1s[(2 * og + 1) * 36 + kq * 4] = r1;
  }
  __syncthreads();

  // ---- layer 2: 64 -> 128, then max over k ----
  {
    const int kq2 = t & 3;   // k block = 8*kq2 .. +8
    const int og2 = t >> 2;  // o = 2*og2, 2*og2+1
    float a2[16];
    float bu = b2[2 * og2], bw = b2[2 * og2 + 1];
#pragma unroll
    for (int i = 0; i < 8; i++) { a2[i] = bu; a2[8 + i] = bw; }
    const float* wr0 = w2 + (2 * og2) * 64;
    const float* wr1 = wr0 + 64;
    for (int c = 0; c < 64; c++) {
      float4 fA = *(const float4*)&h1s[c * 36 + kq2 * 8];
      float4 fB = *(const float4*)&h1s[c * 36 + kq2 * 8 + 4];
      float u = wr0[c], v = wr1[c];
      a2[0] = fmaf(u, fA.x, a2[0]);  a2[1] = fmaf(u, fA.y, a2[1]);
      a2[2] = fmaf(u, fA.z, a2[2]);  a2[3] = fmaf(u, fA.w, a2[3]);
      a2[4] = fmaf(u, fB.x, a2[4]);  a2[5] = fmaf(u, fB.y, a2[5]);
      a2[6] = fmaf(u, fB.z, a2[6]);  a2[7] = fmaf(u, fB.w, a2[7]);
      a2[8] = fmaf(v, fA.x, a2[8]);  a2[9] = fmaf(v, fA.y, a2[9]);
      a2[10] = fmaf(v, fA.z, a2[10]); a2[11] = fmaf(v, fA.w, a2[11]);
      a2[12] = fmaf(v, fB.x, a2[12]); a2[13] = fmaf(v, fB.y, a2[13]);
      a2[14] = fmaf(v, fB.z, a2[14]); a2[15] = fmaf(v, fB.w, a2[15]);
    }
    // relu then max over k == max then relu (relu is monotone)
    float m0 = a2[0], m1 = a2[8];
#pragma unroll
    for (int i = 1; i < 8; i++) { m0 = fmaxf(m0, a2[i]); m1 = fmaxf(m1, a2[8 + i]); }
    m0 = fmaxf(m0, 0.f);
    m1 = fmaxf(m1, 0.f);
    // reduce over the 4 lanes sharing og2 (kq2 = 0..3, adjacent lanes)
    m0 = fmaxf(m0, __shfl_xor(m0, 1, 64));
    m0 = fmaxf(m0, __shfl_xor(m0, 2, 64));
    m1 = fmaxf(m1, __shfl_xor(m1, 1, 64));
    m1 = fmaxf(m1, __shfl_xor(m1, 2, 64));
    if (kq2 == 0) {
      out_np[((size_t)b * 128 + 2 * og2) * NSAMP + s] = m0;
      out_np[((size_t)b * 128 + 2 * og2 + 1) * NSAMP + s] = m1;
    }
  }
}

extern "C" void kernel_launch(void* const* d_in, const int* in_sizes, int n_in,
                              void* d_out, int out_size, void* d_ws, size_t ws_size,
                              hipStream_t stream) {
  (void)in_sizes; (void)n_in; (void)out_size; (void)ws_size;
  const float* xyz = (const float*)d_in[0];
  const float* pts = (const float*)d_in[1];
  const float* att = (const float*)d_in[2];
  const float* w0 = (const float*)d_in[3];
  const float* b0 = (const float*)d_in[4];
  const float* w1 = (const float*)d_in[5];
  const float* b1 = (const float*)d_in[6];
  const float* w2 = (const float*)d_in[7];
  const float* b2 = (const float*)d_in[8];

  float* out = (float*)d_out;
  float* out_newxyz = out;                                     // (B,3,S)
  float* out_newpts = out + NBATCH * 3 * NSAMP;                // (B,128,S)
  float* out_att = out + NBATCH * 3 * NSAMP + NBATCH * 128 * NSAMP;  // (B,1,S)
  int* idx_ws = (int*)d_ws;  // (B*S, K) int32 = 1 MB

  fps_kernel<<<NBATCH, 512, 0, stream>>>(xyz, out_newxyz);
  ballq_kernel<<<(NBATCH * NSAMP) / 4, 256, 0, stream>>>(xyz, att, out_newxyz, idx_ws, out_att);
  mlp_kernel<<<NBATCH * NSAMP, 256, 0, stream>>>(xyz, pts, out_newxyz, idx_ws,
                                                 w0, b0, w1, b1, w2, b2, out_newpts);
}